// Round 1
// 5401.017 us; speedup vs baseline: 1.0082x; 1.0082x over previous
//
#include <hip/hip_runtime.h>

// ---------------------------------------------------------------------------
// DualMemoryLayer (entmax1.5 dual-memory scan), MI355X / gfx950
//   gemm_tn<0>: xz = x @ W_in.T -> XP = silu(lo), SZ = silu(hi)
//   gemm_tn<1>: XW = XP @ W_x.T
//   scan_kernel: 64 persistent WGs (8 per batch).  WG g owns Wh rows
//     [64g,64g+64) AND Ww rows [64g,64g+64) in registers, FULL tape replica
//     in LDS.  Exchange via self-validating stamped 8B relaxed-agent atomics
//     (R4/R6 design, HW-verified).  R7: producers publish hp finalized
//     (+xw+bh) AND local q1/q2 partial dots; entmax sort uses DPP quad_perm.
//   NEW in R8: single-round-trip poll phase.
//     - static remote-slot -> poller map, wave1 NEVER polls (runs entmax(b)
//       with no poll serialized behind it)
//     - own 128 vec + 33 partial slots served from LDS, never via LLC
//     - dual-slot pollers spin on BOTH addresses concurrently (two loads
//       issued per iteration -> one LLC latency, not two serialized)
//     - unified stage[1288] LDS array indexed by slot id (no scatter math)
//   gemm_tn<1>: out = Y @ W_out.T
// ---------------------------------------------------------------------------

#define BB 8
#define TT 1024
#define DD 512
#define NS 32
#define KW 8            // workgroups per batch
#define SLOTS 1288      // 1024 vector slots + 8*33 partial slots

static constexpr float SCALE = 0.044194173824159216f; // 1/sqrt(512)

__device__ __forceinline__ float siluf(float v) { return v / (1.0f + __expf(-v)); }

// ---- cross-lane helpers ----------------------------------------------------
template <int CTRL>
__device__ __forceinline__ float dpp_add(float x) {
  int xi = __builtin_bit_cast(int, x);
  int yi = __builtin_amdgcn_update_dpp(0, xi, CTRL, 0xF, 0xF, false);
  return x + __builtin_bit_cast(float, yi);
}
template <int PAT>
__device__ __forceinline__ float swz_add(float x) {
  int yi = __builtin_amdgcn_ds_swizzle(__builtin_bit_cast(int, x), PAT);
  return x + __builtin_bit_cast(float, yi);
}
// value from lane^J within 32-lane segments; DPP (VALU pipe) for J=1,2
template <int J>
__device__ __forceinline__ float xlane(float x) {
  if constexpr (J == 1) {
    int yi = __builtin_amdgcn_update_dpp(0, __builtin_bit_cast(int, x), 0xB1, 0xF, 0xF, false);
    return __builtin_bit_cast(float, yi);
  } else if constexpr (J == 2) {
    int yi = __builtin_amdgcn_update_dpp(0, __builtin_bit_cast(int, x), 0x4E, 0xF, 0xF, false);
    return __builtin_bit_cast(float, yi);
  } else {
    int yi = __builtin_amdgcn_ds_swizzle(__builtin_bit_cast(int, x), (J << 10) | 0x1F);
    return __builtin_bit_cast(float, yi);
  }
}
// direction-proof sum within each aligned 8-lane group (every lane gets it)
__device__ __forceinline__ float reduce8(float x) {
  x = swz_add<0x041F>(x); // lane ^= 1
  x = swz_add<0x081F>(x); // lane ^= 2
  x = swz_add<0x101F>(x); // lane ^= 4
  return x;
}
// sum over each 32-lane half; every lane of the half gets the sum
__device__ __forceinline__ float reduce32(float x) {
  x = dpp_add<0x121>(x);
  x = dpp_add<0x122>(x);
  x = dpp_add<0x124>(x);
  x = dpp_add<0x128>(x);
  return swz_add<0x401F>(x); // lane ^= 16
}

// ---- exact 1.5-entmax over 32 values, one per lane (width-32 segments) -----
__device__ __forceinline__ float entmax32(float z, int l32) {
  float x = 0.5f * z;
  float m = x;
  m = fmaxf(m, xlane<1>(m));  m = fmaxf(m, xlane<2>(m));
  m = fmaxf(m, xlane<4>(m));  m = fmaxf(m, xlane<8>(m));
  m = fmaxf(m, xlane<16>(m));
  x -= m;
  float s = x; // bitonic sort descending
#define XST(K, J) { float y = xlane<J>(s); bool up = (((l32 & K) == 0) ^ ((l32 & J) == 0)); s = up ? fminf(s, y) : fmaxf(s, y); }
  XST(2, 1)
  XST(4, 2)  XST(4, 1)
  XST(8, 4)  XST(8, 2)  XST(8, 1)
  XST(16, 8) XST(16, 4) XST(16, 2) XST(16, 1)
  XST(32, 16) XST(32, 8) XST(32, 4) XST(32, 2) XST(32, 1)
#undef XST
  float cs = s, cq = s * s; // inclusive prefix sums
  #pragma unroll
  for (int d = 1; d < 32; d <<= 1) {
    float ts = __shfl_up(cs, d, 32);
    float tq = __shfl_up(cq, d, 32);
    if (l32 >= d) { cs += ts; cq += tq; }
  }
  float kf    = (float)(l32 + 1);
  float mean  = cs / kf;
  float msq   = cq / kf;
  float ssv   = kf * (msq - mean * mean);
  float delta = (1.0f - ssv) / kf;
  float tau   = mean - sqrtf(fmaxf(delta, 0.0f));
  unsigned long long mask = __ballot(tau <= s);
  int support = __popcll(mask & 0xFFFFFFFFull) - 1;
  float tau_star = __shfl(tau, support, 32);
  float p = fmaxf(x - tau_star, 0.0f);
  return p * p;
}

// ---- stamped exchange primitives (R4/R6-verified) --------------------------
__device__ __forceinline__ void pubv(unsigned long long* p, int t, float v) {
  unsigned long long u = ((unsigned long long)(unsigned)(t + 1) << 32) |
                         (unsigned long long)__builtin_bit_cast(unsigned, v);
  __hip_atomic_store(p, u, __ATOMIC_RELAXED, __HIP_MEMORY_SCOPE_AGENT);
}

// ---------------------------------------------------------------------------
// Tiled fp32 GEMM:  C[M,N] = A[M,K] @ B[N,K]^T
// ---------------------------------------------------------------------------
template <int MODE>
__global__ __launch_bounds__(256) void gemm_tn(const float* __restrict__ A,
                                               const float* __restrict__ Bm,
                                               float* __restrict__ C0,
                                               float* __restrict__ C1,
                                               int M, int N, int K) {
  const int bm = blockIdx.x, bn = blockIdx.y;
  const int tid = threadIdx.x;
  const int tx = tid & 15, ty = tid >> 4;
  __shared__ __align__(16) float As[16][132];
  __shared__ __align__(16) float Bs[16][132];
  float acc[8][8] = {};
  const int rowA0 = bm * 128, rowB0 = bn * 128;

  for (int k0 = 0; k0 < K; k0 += 16) {
    #pragma unroll
    for (int q = 0; q < 2; ++q) {
      int idx = tid + q * 256;
      int r   = idx >> 2;
      int kq  = (idx & 3) * 4;
      float4 a4 = *(const float4*)&A [(size_t)(rowA0 + r) * K + k0 + kq];
      float4 b4 = *(const float4*)&Bm[(size_t)(rowB0 + r) * K + k0 + kq];
      As[kq + 0][r] = a4.x; As[kq + 1][r] = a4.y; As[kq + 2][r] = a4.z; As[kq + 3][r] = a4.w;
      Bs[kq + 0][r] = b4.x; Bs[kq + 1][r] = b4.y; Bs[kq + 2][r] = b4.z; Bs[kq + 3][r] = b4.w;
    }
    __syncthreads();
    #pragma unroll
    for (int kk = 0; kk < 16; ++kk) {
      float4 a0 = *(const float4*)&As[kk][ty * 8];
      float4 a1 = *(const float4*)&As[kk][ty * 8 + 4];
      float4 b0 = *(const float4*)&Bs[kk][tx * 8];
      float4 b1 = *(const float4*)&Bs[kk][tx * 8 + 4];
      float av[8] = {a0.x, a0.y, a0.z, a0.w, a1.x, a1.y, a1.z, a1.w};
      float bv[8] = {b0.x, b0.y, b0.z, b0.w, b1.x, b1.y, b1.z, b1.w};
      #pragma unroll
      for (int i = 0; i < 8; ++i)
        #pragma unroll
        for (int j = 0; j < 8; ++j) acc[i][j] = fmaf(av[i], bv[j], acc[i][j]);
    }
    __syncthreads();
  }
  #pragma unroll
  for (int i = 0; i < 8; ++i) {
    int gr = rowA0 + ty * 8 + i;
    #pragma unroll
    for (int j = 0; j < 8; ++j) {
      int gc = rowB0 + tx * 8 + j;
      float v = acc[i][j];
      if (MODE == 0) {
        float sv = siluf(v);
        if (gc < 512) C0[(size_t)gr * 512 + gc]         = sv;
        else          C1[(size_t)gr * 512 + (gc - 512)] = sv;
      } else {
        C0[(size_t)gr * N + gc] = v;
      }
    }
  }
}

// ---------------------------------------------------------------------------
// Persistent scan.  WG (b = blk&7, g = blk>>3), 1024 threads.
// Slot layout per (parity,batch): [0,1024): vector s = g*128 + i (i<64 hp_d,
// else wvv_d, d = g*64 + (i&63));  [1024,1288): s = 1024 + g*33 + j
// (j<32: q1p[j], j==32: q2p).
// stage[SLOTS] in LDS mirrors the slot space; own slots filled from local
// data, remote slots filled by the static poller map (wave1 excluded).
// ---------------------------------------------------------------------------
__global__ __launch_bounds__(1024) void scan_kernel(
    const float* __restrict__ Wh, const float* __restrict__ Ww,
    const float* __restrict__ bh, const float* __restrict__ XW,
    const float* __restrict__ SZ, float* __restrict__ Y,
    unsigned long long* __restrict__ Pp,  // [2][BB][SLOTS]
    float* __restrict__ outTape, float* __restrict__ outWork) {
  const int tid  = threadIdx.x;
  const int wv   = tid >> 6, lane = tid & 63;
  const int b    = blockIdx.x & 7, g = blockIdx.x >> 3;
  const int l32  = lane & 31;
  const int seg  = tid & 7;         // column segment (8 per row)
  const int row  = tid >> 3;        // local row 0..127 (<64: Wh, else Ww)

  __shared__ __align__(16) float tape[NS][DD];    // full tape replica
  __shared__ __align__(16) float stage[SLOTS];    // gathered slot values
  __shared__ float h_full[DD];
  __shared__ float hp_loc[64], wv_loc[64];
  __shared__ float ws_arr[NS];
  __shared__ float bArr[NS], aArr[NS];

  // stationary weights: 64 floats = row (Wh or Ww row g*64 + (row&63)),
  // cols seg*64..seg*64+63, bank-swizzled load order
  float w[64];
  {
    const float* src = (row < 64) ? (Wh + (size_t)(g * 64 + row) * DD)
                                  : (Ww + (size_t)(g * 64 + row - 64) * DD);
    #pragma unroll
    for (int q = 0; q < 16; ++q) {
      int c4 = seg * 64 + ((4 * q + 4 * seg) & 63);
      float4 v4 = *(const float4*)(src + c4);
      w[4*q+0] = v4.x; w[4*q+1] = v4.y; w[4*q+2] = v4.z; w[4*q+3] = v4.w;
    }
  }
  const float bhv = (seg == 0 && row < 64) ? bh[g * 64 + row] : 0.f;
  for (int e = tid; e < NS * DD; e += 1024) ((float*)tape)[e] = 0.f;
  if (tid < DD) h_full[tid] = 0.f;

  // ---- static poller map (computed once) -----------------------------------
  // pollers = all threads except wave1 (tid 64..127): p in [0,960)
  // remote slots (1127 of 1288): vec minus own 128, partials minus own 33.
  //   remote(i): i<896 -> vec slot i (+128 if past own range)
  //              else  -> partial r2=i-896 (+33 if past own range), +1024
  // primary slot = remote(p); secondary = remote(960+p) for p<167.
  const int p = (tid < 64) ? tid : (tid >= 128 ? tid - 64 : -1);
  int slotA = 0, slotBr = -1;
  if (p >= 0) {
    slotA = (p < 896) ? (p + (p >= g * 128 ? 128 : 0))
                      : (1024 + (p - 896) + ((p - 896) >= g * 33 ? 33 : 0));
    if (p < 167) {
      int r2 = (960 + p) - 896;                 // 64..230, all partial-remote
      slotBr = 1024 + r2 + (r2 >= g * 33 ? 33 : 0);
    }
  }
  const int slotB = (slotBr >= 0) ? slotBr : slotA;  // safe dummy address
  __syncthreads();

  for (int t = 0; t <= TT; ++t) {
    unsigned long long* pbuf = Pp + ((size_t)(t & 1) * BB + b) * SLOTS;
    // prefetch own-row xw and own-slice sz (latency hidden under matvec)
    float xwv = 0.f;
    if (seg == 0 && row < 64 && t < TT)
      xwv = XW[((size_t)b * TT + t) * DD + g * 64 + row];
    float szv = 0.f;
    if (t < TT && tid < DD && (tid >> 6) == g)
      szv = SZ[((size_t)b * TT + t) * DD + tid];

    // ---- row-slice matvec: pv = sum over my 64 cols of W[row]*h ----
    float pv = 0.f;
    #pragma unroll
    for (int q = 0; q < 16; ++q) {
      int c4 = seg * 64 + ((4 * q + 4 * seg) & 63);   // bank-conflict-free
      float4 h4 = *(const float4*)&h_full[c4];
      pv = fmaf(w[4*q+0], h4.x, pv);
      pv = fmaf(w[4*q+1], h4.y, pv);
      pv = fmaf(w[4*q+2], h4.z, pv);
      pv = fmaf(w[4*q+3], h4.w, pv);
    }
    pv = reduce8(pv);            // xor butterfly: every lane has the row sum
    if (seg == 0) {
      float hv = (row < 64) ? (pv + xwv + bhv) : pv;   // hp finalized
      if (row < 64) hp_loc[row] = hv; else wv_loc[row - 64] = hv;
      pubv(&pbuf[g * 128 + row], t, hv);
    }
    __syncthreads();  // SYNC1: hp_loc / wv_loc ready

    // ---- local partial dots on own d-slice (tape is pre-update) ----
    {
      int n = wv * 2 + (lane >> 5);
      float s1 = fmaf(tape[n][g * 64 + 2 * l32],     hp_loc[2 * l32],
               tape[n][g * 64 + 2 * l32 + 1] * hp_loc[2 * l32 + 1]);
      s1 = reduce32(s1);
      if (l32 == 0) {
        pubv(&pbuf[1024 + g * 33 + n], t, s1);
        stage[1024 + g * 33 + n] = s1;      // own partial served from LDS
      }
      if (wv == 0 && lane < 32) {
        float s2 = fmaf(wv_loc[l32], hp_loc[l32],
                        wv_loc[l32 + 32] * hp_loc[l32 + 32]);
        s2 = reduce32(s2);
        if (l32 == 0) {
          pubv(&pbuf[1024 + g * 33 + 32], t, s2);
          stage[1024 + g * 33 + 32] = s2;
        }
      }
    }
    // ---- ws = tape . h_prev (full, local; slot n = wv*2 + half) ----
    {
      int n = wv * 2 + (lane >> 5);
      float sw = 0.f;
      #pragma unroll
      for (int j = 0; j < 16; ++j)
        sw = fmaf(tape[n][l32 + 32 * j], h_full[l32 + 32 * j], sw);
      sw = reduce32(sw);
      if (l32 == 0) ws_arr[n] = sw * SCALE;
    }
    __syncthreads();  // SYNC2

    // own vector slots: LDS, no LLC round trip
    if (tid >= g * 128 && tid < g * 128 + 128) {
      int i = tid & 127;
      stage[tid] = (i < 64) ? hp_loc[i] : wv_loc[i - 64];
    }
    if (wv == 1) {
      // wave1 never polls: entmax(b) has no LLC latency serialized behind it
      float pb = entmax32(ws_arr[l32], l32);
      if (lane < NS) bArr[lane] = pb;
    } else {
      // concurrent dual-slot spin: both loads issued per iteration ->
      // poll phase costs ~one LLC round trip after the last publish
      const unsigned want = (unsigned)(t + 1);
      bool d1 = false, d2 = (slotBr < 0);
      float v1 = 0.f, v2 = 0.f;
      const unsigned long long* a1 = &pbuf[slotA];
      const unsigned long long* a2 = &pbuf[slotB];
      do {
        unsigned long long u1 = __hip_atomic_load(a1, __ATOMIC_RELAXED, __HIP_MEMORY_SCOPE_AGENT);
        unsigned long long u2 = __hip_atomic_load(a2, __ATOMIC_RELAXED, __HIP_MEMORY_SCOPE_AGENT);
        if (!d1 && (unsigned)(u1 >> 32) == want) {
          v1 = __builtin_bit_cast(float, (unsigned)(u1 & 0xFFFFFFFFu)); d1 = true;
        }
        if (!d2 && (unsigned)(u2 >> 32) == want) {
          v2 = __builtin_bit_cast(float, (unsigned)(u2 & 0xFFFFFFFFu)); d2 = true;
        }
      } while (!(d1 && d2));
      stage[slotA] = v1;
      if (slotBr >= 0) stage[slotBr] = v2;
    }
    __syncthreads();  // SYNC3: stage fully populated, bArr ready

    // ---- wave0: rs from summed partials + entmax(a);  others: tape update --
    if (wv == 0) {
      if (t < TT) {
        float q1s = 0.f, q2s = 0.f;
        #pragma unroll
        for (int k = 0; k < KW; ++k) {
          q1s += stage[1024 + k * 33 + l32];
          q2s += stage[1024 + k * 33 + 32];
        }
        float pb = bArr[l32];
        float rs = SCALE * fmaf(pb, q2s - q1s, q1s);
        float pa = entmax32(rs, l32);
        if (lane < NS) aArr[lane] = pa;
      }
    } else {
      for (int e = tid - 64; e < NS * DD / 4; e += 960) {
        int n = e >> 7, dq = (e & 127) * 4;
        float  bn = bArr[n];
        float4 tv = *(float4*)&tape[n][dq];
        const float4 wq = *(const float4*)&stage[((dq >> 6) << 7) + 64 + (dq & 63)];
        tv.x = fmaf(bn, wq.x - tv.x, tv.x);
        tv.y = fmaf(bn, wq.y - tv.y, tv.y);
        tv.z = fmaf(bn, wq.z - tv.z, tv.z);
        tv.w = fmaf(bn, wq.w - tv.w, tv.w);
        *(float4*)&tape[n][dq] = tv;
      }
    }
    __syncthreads();  // SYNC4: aArr + tape_new ready

    if (t == TT) {  // final outputs: tape_T and h_{T-1}
      if (tid < DD && (tid >> 6) == g) outWork[(size_t)b * DD + tid] = h_full[tid];
      for (int e = tid; e < NS * 64; e += 1024) {
        int n = e >> 6, d = g * 64 + (e & 63);
        outTape[((size_t)b * NS + n) * DD + d] = tape[n][d];
      }
      break;
    }
    // ---- read + h_t = tanh(hp + read);  Y for own slice ----
    if (tid < DD) {
      float r = 0.f;
      #pragma unroll
      for (int n = 0; n < NS; ++n) r = fmaf(aArr[n], tape[n][tid], r);
      float hn = tanhf(stage[((tid >> 6) << 7) + (tid & 63)] + r);
      if ((tid >> 6) == g)
        Y[((size_t)b * TT + t) * DD + tid] = hn * szv;
      h_full[tid] = hn;
    }
    __syncthreads();  // SYNC5
  }
}

// ---------------------------------------------------------------------------
extern "C" void kernel_launch(void* const* d_in, const int* in_sizes, int n_in,
                              void* d_out, int out_size, void* d_ws, size_t ws_size,
                              hipStream_t stream) {
  (void)in_sizes; (void)n_in; (void)out_size; (void)ws_size;
  const float* x    = (const float*)d_in[0];
  const float* W_in = (const float*)d_in[1];
  const float* W_out= (const float*)d_in[2];
  const float* W_h  = (const float*)d_in[3];
  const float* W_x  = (const float*)d_in[4];
  const float* b_h  = (const float*)d_in[5];
  const float* W_wr = (const float*)d_in[6];

  float* out     = (float*)d_out;                  // [B,T,D]
  float* outTape = out + (size_t)BB * TT * DD;     // [B,NS,D]
  float* outWork = outTape + (size_t)BB * NS * DD; // [B,D]

  float* wsf  = (float*)d_ws;
  float* XP   = wsf;                               // [8192,512] (Y after scan)
  float* SZ   = XP + (size_t)BB * TT * DD;
  float* XWb  = SZ + (size_t)BB * TT * DD;
  unsigned long long* Pp = (unsigned long long*)(XWb + (size_t)BB * TT * DD);
  // Pp: [2][BB][SLOTS] = 161 KB.  No init needed: 0xAA poison stamp never
  // equals any wanted stamp t+1 (1..1025).

  gemm_tn<0><<<dim3(64, 8), 256, 0, stream>>>(x, W_in, XP, SZ, BB * TT, 2 * DD, DD);
  gemm_tn<1><<<dim3(64, 4), 256, 0, stream>>>(XP, W_x, XWb, nullptr, BB * TT, DD, DD);
  scan_kernel<<<64, 1024, 0, stream>>>(W_h, W_wr, b_h, XWb, SZ, XP,
                                       Pp, outTape, outWork);
  gemm_tn<1><<<dim3(64, 4), 256, 0, stream>>>(XP, W_out, out, nullptr, BB * TT, DD, DD);
}